// Round 1
// baseline (717.661 us; speedup 1.0000x reference)
//
#include <hip/hip_runtime.h>

#define IN_DIM 4096
#define OUT_DIM 4096
#define NTOK 8192
#define LORA_SCALE 2.0f   // alpha/rank = 32/16

typedef __bf16 bf16x8 __attribute__((ext_vector_type(8)));
typedef float f32x4 __attribute__((ext_vector_type(4)));

__device__ __constant__ float NF4_CB[16] = {
    -1.0f, -0.6961928009986877f, -0.5250730514526367f, -0.39491748809814453f,
    -0.28444138169288635f, -0.18477343022823334f, -0.09105003625154495f, 0.0f,
    0.07958029955625534f, 0.16093020141124725f, 0.24611230194568634f,
    0.33791524171829224f, 0.44070982933044434f, 0.5626170039176941f,
    0.7229568362236023f, 1.0f};

// async global->LDS, 16B per lane; LDS dest is wave-uniform base + lane*16
#define GLOAD16(g, l)                                                         \
  __builtin_amdgcn_global_load_lds(                                           \
      (const __attribute__((address_space(1))) void*)(g),                     \
      (__attribute__((address_space(3))) void*)(l), 16, 0, 0)

// ---------------------------------------------------------------------------
// Kernel 1: W_eff[o][k] = NF4_CB[code]*scaler + 2 * sum_r B[o][r]*A[r][k]
// (LoRA folded into the dequantized weight; bf16 output)
// 8 elements per thread along k.
// ---------------------------------------------------------------------------
__global__ __launch_bounds__(256) void nf4_weff_kernel(
    const int* __restrict__ codes, const float* __restrict__ scalers,
    const float* __restrict__ la, const float* __restrict__ lb,
    __bf16* __restrict__ weff) {
  size_t base = ((size_t)blockIdx.x * 256 + threadIdx.x) * 8;
  int o = (int)(base >> 12);          // /IN_DIM
  int k = (int)(base & (IN_DIM - 1));
  float sc = scalers[base >> 6];      // one 64-block per 8-chunk
  const int4 c0 = *(const int4*)(codes + base);
  const int4 c1 = *(const int4*)(codes + base + 4);
  float v[8];
  v[0] = NF4_CB[c0.x] * sc; v[1] = NF4_CB[c0.y] * sc;
  v[2] = NF4_CB[c0.z] * sc; v[3] = NF4_CB[c0.w] * sc;
  v[4] = NF4_CB[c1.x] * sc; v[5] = NF4_CB[c1.y] * sc;
  v[6] = NF4_CB[c1.z] * sc; v[7] = NF4_CB[c1.w] * sc;
  const float* lbo = lb + o * 16;
#pragma unroll
  for (int r = 0; r < 16; ++r) {
    float br = LORA_SCALE * lbo[r];
    const float4 a0 = *(const float4*)(la + r * IN_DIM + k);
    const float4 a1 = *(const float4*)(la + r * IN_DIM + k + 4);
    v[0] += br * a0.x; v[1] += br * a0.y; v[2] += br * a0.z; v[3] += br * a0.w;
    v[4] += br * a1.x; v[5] += br * a1.y; v[6] += br * a1.z; v[7] += br * a1.w;
  }
  union { __bf16 h[8]; int4 i4; } u;
#pragma unroll
  for (int t = 0; t < 8; ++t) u.h[t] = (__bf16)v[t];
  *(int4*)(weff + base) = u.i4;
}

// ---------------------------------------------------------------------------
// Kernel 2: x f32 -> bf16 (8 elems/thread)
// ---------------------------------------------------------------------------
__global__ __launch_bounds__(256) void xcvt_kernel(const float* __restrict__ x,
                                                   __bf16* __restrict__ xb) {
  size_t g = ((size_t)blockIdx.x * 256 + threadIdx.x) * 8;
  const float4 a = *(const float4*)(x + g);
  const float4 b = *(const float4*)(x + g + 4);
  union { __bf16 h[8]; int4 i4; } u;
  u.h[0] = (__bf16)a.x; u.h[1] = (__bf16)a.y;
  u.h[2] = (__bf16)a.z; u.h[3] = (__bf16)a.w;
  u.h[4] = (__bf16)b.x; u.h[5] = (__bf16)b.y;
  u.h[6] = (__bf16)b.z; u.h[7] = (__bf16)b.w;
  *(int4*)(xb + g) = u.i4;
}

// ---------------------------------------------------------------------------
// Kernel 3: C[M,N] = Xb[M,K] @ Weff[N,K]^T   (bf16 in, f32 out)
// m97 structure: 128x128 block tile, BK=32, 4 waves in 2x2, each wave a
// 64x64 subtile via 4x4 grid of v_mfma_f32_16x16x32_bf16.
// ---------------------------------------------------------------------------
__global__ __launch_bounds__(256) void gemm_bt_kernel(
    const __bf16* __restrict__ A,   // [8192, 4096] x in bf16
    const __bf16* __restrict__ B,   // [4096, 4096] W_eff in bf16
    float* __restrict__ C) {        // [8192, 4096] f32
  const int K = IN_DIM;
  const int N = OUT_DIM;
  __shared__ __align__(16) __bf16 lA[128 * 32];
  __shared__ __align__(16) __bf16 lB[128 * 32];

  const int n0 = blockIdx.x * 128;
  const int m0 = blockIdx.y * 128;
  const int tid = threadIdx.x;
  const int wave = tid >> 6;
  const int lane = tid & 63;
  const int wrow = wave >> 1;   // wave's 64-row group in tile
  const int wcol = wave & 1;    // wave's 64-col group in tile

  // staging: lane covers row (wave*16 + lane/4), 16B at col (lane%4)*8 elems
  const int srow = lane >> 2;
  const int scol = (lane & 3) * 8;
  const __bf16* gA = A + (size_t)(m0 + wave * 16 + srow) * K + scol;
  const __bf16* gB = B + (size_t)(n0 + wave * 16 + srow) * K + scol;
  __bf16* lAw = lA + wave * 16 * 32;   // wave-uniform LDS base
  __bf16* lBw = lB + wave * 16 * 32;

  f32x4 acc[4][4] = {};
  const int lm = lane & 15;            // row within 16x16 frag
  const int lk = (lane >> 4) * 8;      // k offset within 32

  for (int k0 = 0; k0 < K; k0 += 32) {
    __syncthreads();  // previous compute done before overwrite
    GLOAD16(gA + k0, lAw);
    GLOAD16(gA + k0 + (size_t)64 * K, lAw + 64 * 32);
    GLOAD16(gB + k0, lBw);
    GLOAD16(gB + k0 + (size_t)64 * K, lBw + 64 * 32);
    __syncthreads();  // compiler emits vmcnt(0) drain before s_barrier

    const __bf16* aw = lA + (wrow * 64 + lm) * 32 + lk;
    const __bf16* bw = lB + (wcol * 64 + lm) * 32 + lk;
    bf16x8 af[4], bfp[4];
#pragma unroll
    for (int i = 0; i < 4; ++i) af[i] = *(const bf16x8*)(aw + i * 16 * 32);
#pragma unroll
    for (int j = 0; j < 4; ++j) bfp[j] = *(const bf16x8*)(bw + j * 16 * 32);
#pragma unroll
    for (int i = 0; i < 4; ++i)
#pragma unroll
      for (int j = 0; j < 4; ++j)
        acc[i][j] = __builtin_amdgcn_mfma_f32_16x16x32_bf16(af[i], bfp[j],
                                                            acc[i][j], 0, 0, 0);
  }

  // epilogue: D row = 4*(lane>>4)+r, col = lane&15 within each 16x16 tile
  const int crow0 = m0 + wrow * 64 + 4 * (lane >> 4);
  const int ccol0 = n0 + wcol * 64 + (lane & 15);
#pragma unroll
  for (int i = 0; i < 4; ++i)
#pragma unroll
    for (int j = 0; j < 4; ++j)
#pragma unroll
      for (int r = 0; r < 4; ++r)
        C[(size_t)(crow0 + i * 16 + r) * N + ccol0 + j * 16] = acc[i][j][r];
}

extern "C" void kernel_launch(void* const* d_in, const int* in_sizes, int n_in,
                              void* d_out, int out_size, void* d_ws,
                              size_t ws_size, hipStream_t stream) {
  const float* x = (const float*)d_in[0];       // [8192,4096]
  const int* codes = (const int*)d_in[1];       // [262144,64]
  const float* scalers = (const float*)d_in[2]; // [262144]
  const float* la = (const float*)d_in[3];      // [16,4096]
  const float* lb = (const float*)d_in[4];      // [4096,16]
  float* out = (float*)d_out;                   // [8192,4096]

  __bf16* xb = (__bf16*)d_ws;                                   // 64 MB
  __bf16* weff = (__bf16*)((char*)d_ws + (size_t)NTOK * IN_DIM * 2); // 32 MB

  xcvt_kernel<<<NTOK * IN_DIM / (256 * 8), 256, 0, stream>>>(x, xb);
  nf4_weff_kernel<<<OUT_DIM * IN_DIM / (256 * 8), 256, 0, stream>>>(
      codes, scalers, la, lb, weff);
  gemm_bt_kernel<<<dim3(OUT_DIM / 128, NTOK / 128), 256, 0, stream>>>(xb, weff,
                                                                      out);
}

// Round 2
// 702.419 us; speedup vs baseline: 1.0217x; 1.0217x over previous
//
#include <hip/hip_runtime.h>

#define IN_DIM 4096
#define OUT_DIM 4096
#define NTOK 8192
#define LORA_SCALE 2.0f   // alpha/rank = 32/16

typedef __bf16 bf16x8 __attribute__((ext_vector_type(8)));
typedef float f32x4 __attribute__((ext_vector_type(4)));

__device__ __constant__ float NF4_CB[16] = {
    -1.0f, -0.6961928009986877f, -0.5250730514526367f, -0.39491748809814453f,
    -0.28444138169288635f, -0.18477343022823334f, -0.09105003625154495f, 0.0f,
    0.07958029955625534f, 0.16093020141124725f, 0.24611230194568634f,
    0.33791524171829224f, 0.44070982933044434f, 0.5626170039176941f,
    0.7229568362236023f, 1.0f};

// async global->LDS, 16B per lane; LDS dest is wave-uniform base + lane*16
#define GLOAD16(g, l)                                                         \
  __builtin_amdgcn_global_load_lds(                                           \
      (const __attribute__((address_space(1))) void*)(g),                     \
      (__attribute__((address_space(3))) void*)(l), 16, 0, 0)

// ---------------------------------------------------------------------------
// Kernel 1: W_eff[o][k] = NF4_CB[code]*scaler + 2 * sum_r B[o][r]*A[r][k]
// Codebook lookup via ds_bpermute (__shfl) instead of per-lane scattered
// loads from __constant__.
// ---------------------------------------------------------------------------
__global__ __launch_bounds__(256) void nf4_weff_kernel(
    const int* __restrict__ codes, const float* __restrict__ scalers,
    const float* __restrict__ la, const float* __restrict__ lb,
    __bf16* __restrict__ weff) {
  const int lane = threadIdx.x & 63;
  const float cbv = NF4_CB[lane & 15];  // lanes 0..15 hold the table
  size_t base = ((size_t)blockIdx.x * 256 + threadIdx.x) * 8;
  int o = (int)(base >> 12);          // /IN_DIM
  int k = (int)(base & (IN_DIM - 1));
  float sc = scalers[base >> 6];      // one 64-block per 8-chunk
  const int4 c0 = *(const int4*)(codes + base);
  const int4 c1 = *(const int4*)(codes + base + 4);
  float v[8];
  v[0] = __shfl(cbv, c0.x, 64) * sc; v[1] = __shfl(cbv, c0.y, 64) * sc;
  v[2] = __shfl(cbv, c0.z, 64) * sc; v[3] = __shfl(cbv, c0.w, 64) * sc;
  v[4] = __shfl(cbv, c1.x, 64) * sc; v[5] = __shfl(cbv, c1.y, 64) * sc;
  v[6] = __shfl(cbv, c1.z, 64) * sc; v[7] = __shfl(cbv, c1.w, 64) * sc;
  const float* lbo = lb + o * 16;
#pragma unroll
  for (int r = 0; r < 16; ++r) {
    float br = LORA_SCALE * lbo[r];
    const float4 a0 = *(const float4*)(la + r * IN_DIM + k);
    const float4 a1 = *(const float4*)(la + r * IN_DIM + k + 4);
    v[0] += br * a0.x; v[1] += br * a0.y; v[2] += br * a0.z; v[3] += br * a0.w;
    v[4] += br * a1.x; v[5] += br * a1.y; v[6] += br * a1.z; v[7] += br * a1.w;
  }
  union { __bf16 h[8]; int4 i4; } u;
#pragma unroll
  for (int t = 0; t < 8; ++t) u.h[t] = (__bf16)v[t];
  *(int4*)(weff + base) = u.i4;
}

// ---------------------------------------------------------------------------
// Kernel 2: x f32 -> bf16 (8 elems/thread)
// ---------------------------------------------------------------------------
__global__ __launch_bounds__(256) void xcvt_kernel(const float* __restrict__ x,
                                                   __bf16* __restrict__ xb) {
  size_t g = ((size_t)blockIdx.x * 256 + threadIdx.x) * 8;
  const float4 a = *(const float4*)(x + g);
  const float4 b = *(const float4*)(x + g + 4);
  union { __bf16 h[8]; int4 i4; } u;
  u.h[0] = (__bf16)a.x; u.h[1] = (__bf16)a.y;
  u.h[2] = (__bf16)a.z; u.h[3] = (__bf16)a.w;
  u.h[4] = (__bf16)b.x; u.h[5] = (__bf16)b.y;
  u.h[6] = (__bf16)b.z; u.h[7] = (__bf16)b.w;
  *(int4*)(xb + g) = u.i4;
}

// ---------------------------------------------------------------------------
// Kernel 3: C[M,N] = Xb[M,K] @ Weff[N,K]^T   (bf16 in, f32 out)
// 128x128 tile, BK=32, 4 waves 2x2, 64x64/wave via 4x4 of 16x16x32 MFMA.
// LDS chunk-XOR swizzle: 16B unit (row, slot) holds global chunk
// slot ^ ((row>>1)&3)  -> 8-way read bank conflicts become 2-way (free).
// Grid swizzle: 16m x 16n supertiles for L2/L3 locality.
// ---------------------------------------------------------------------------
__global__ __launch_bounds__(256) void gemm_bt_kernel(
    const __bf16* __restrict__ A,   // [8192, 4096] x in bf16
    const __bf16* __restrict__ B,   // [4096, 4096] W_eff in bf16
    float* __restrict__ C) {        // [8192, 4096] f32
  const int K = IN_DIM;
  const int N = OUT_DIM;
  __shared__ __align__(16) __bf16 lA[128 * 32];
  __shared__ __align__(16) __bf16 lB[128 * 32];

  // supertile swizzle: 256 consecutive blocks cover 16m x 16n (n fastest)
  const int lin = blockIdx.y * gridDim.x + blockIdx.x;   // 0..2047
  const int super = lin >> 8;                            // 0..7
  const int within = lin & 255;
  const int m0 = ((super >> 1) * 16 + (within >> 4)) * 128;
  const int n0 = ((super & 1) * 16 + (within & 15)) * 128;

  const int tid = threadIdx.x;
  const int wave = tid >> 6;
  const int lane = tid & 63;
  const int wrow = wave >> 1;   // wave's 64-row group in tile
  const int wcol = wave & 1;    // wave's 64-col group in tile

  // staging: lane covers local row (wave*16 + lane/4); chunk XOR-swizzled.
  // swz(row) = (row>>1)&3; for row = wave*16 + (lane>>2): swz = (lane>>3)&3
  // (rows +64 have identical swz). Global chunk permutation stays within the
  // same 64B line -> still fully coalesced.
  const int srow = lane >> 2;
  const int schunk = (lane & 3) ^ ((lane >> 3) & 3);
  const int scol = schunk * 8;
  const __bf16* gA = A + (size_t)(m0 + wave * 16 + srow) * K + scol;
  const __bf16* gB = B + (size_t)(n0 + wave * 16 + srow) * K + scol;
  __bf16* lAw = lA + wave * 16 * 32;   // wave-uniform LDS base
  __bf16* lBw = lB + wave * 16 * 32;

  f32x4 acc[4][4] = {};
  const int lm = lane & 15;            // row within 16x16 frag
  // read slot = c ^ swz(row); c = lane>>4, swz = (lane>>1)&3 (bits 1-2 of lm)
  const int lk = (((lane >> 4) ^ ((lane >> 1) & 3)) * 8);

  for (int k0 = 0; k0 < K; k0 += 32) {
    __syncthreads();  // previous compute done before overwrite
    GLOAD16(gA + k0, lAw);
    GLOAD16(gA + k0 + (size_t)64 * K, lAw + 64 * 32);
    GLOAD16(gB + k0, lBw);
    GLOAD16(gB + k0 + (size_t)64 * K, lBw + 64 * 32);
    __syncthreads();  // vmcnt(0) drain before s_barrier

    const __bf16* aw = lA + (wrow * 64 + lm) * 32 + lk;
    const __bf16* bw = lB + (wcol * 64 + lm) * 32 + lk;
    bf16x8 af[4], bfp[4];
#pragma unroll
    for (int i = 0; i < 4; ++i) af[i] = *(const bf16x8*)(aw + i * 16 * 32);
#pragma unroll
    for (int j = 0; j < 4; ++j) bfp[j] = *(const bf16x8*)(bw + j * 16 * 32);
#pragma unroll
    for (int i = 0; i < 4; ++i)
#pragma unroll
      for (int j = 0; j < 4; ++j)
        acc[i][j] = __builtin_amdgcn_mfma_f32_16x16x32_bf16(af[i], bfp[j],
                                                            acc[i][j], 0, 0, 0);
  }

  // epilogue: D row = 4*(lane>>4)+r, col = lane&15 within each 16x16 tile
  const int crow0 = m0 + wrow * 64 + 4 * (lane >> 4);
  const int ccol0 = n0 + wcol * 64 + (lane & 15);
#pragma unroll
  for (int i = 0; i < 4; ++i)
#pragma unroll
    for (int j = 0; j < 4; ++j)
#pragma unroll
      for (int r = 0; r < 4; ++r)
        C[(size_t)(crow0 + i * 16 + r) * N + ccol0 + j * 16] = acc[i][j][r];
}

extern "C" void kernel_launch(void* const* d_in, const int* in_sizes, int n_in,
                              void* d_out, int out_size, void* d_ws,
                              size_t ws_size, hipStream_t stream) {
  const float* x = (const float*)d_in[0];       // [8192,4096]
  const int* codes = (const int*)d_in[1];       // [262144,64]
  const float* scalers = (const float*)d_in[2]; // [262144]
  const float* la = (const float*)d_in[3];      // [16,4096]
  const float* lb = (const float*)d_in[4];      // [4096,16]
  float* out = (float*)d_out;                   // [8192,4096]

  __bf16* xb = (__bf16*)d_ws;                                        // 64 MB
  __bf16* weff = (__bf16*)((char*)d_ws + (size_t)NTOK * IN_DIM * 2); // 32 MB

  xcvt_kernel<<<NTOK * IN_DIM / (256 * 8), 256, 0, stream>>>(x, xb);
  nf4_weff_kernel<<<OUT_DIM * IN_DIM / (256 * 8), 256, 0, stream>>>(
      codes, scalers, la, lb, weff);
  gemm_bt_kernel<<<dim3(OUT_DIM / 128, NTOK / 128), 256, 0, stream>>>(xb, weff,
                                                                      out);
}

// Round 3
// 650.421 us; speedup vs baseline: 1.1034x; 1.0799x over previous
//
#include <hip/hip_runtime.h>

#define IN_DIM 4096
#define OUT_DIM 4096
#define NTOK 8192
#define LORA_SCALE 2.0f   // alpha/rank = 32/16

typedef __bf16 bf16x8 __attribute__((ext_vector_type(8)));
typedef float f32x4 __attribute__((ext_vector_type(4)));

__device__ __constant__ float NF4_CB[16] = {
    -1.0f, -0.6961928009986877f, -0.5250730514526367f, -0.39491748809814453f,
    -0.28444138169288635f, -0.18477343022823334f, -0.09105003625154495f, 0.0f,
    0.07958029955625534f, 0.16093020141124725f, 0.24611230194568634f,
    0.33791524171829224f, 0.44070982933044434f, 0.5626170039176941f,
    0.7229568362236023f, 1.0f};

// async global->LDS, 16B per lane; LDS dest is wave-uniform base + lane*16
#define GLOAD16(g, l)                                                         \
  __builtin_amdgcn_global_load_lds(                                           \
      (const __attribute__((address_space(1))) void*)(g),                     \
      (__attribute__((address_space(3))) void*)(l), 16, 0, 0)

#define XCVT_BLOCKS (NTOK * IN_DIM / (256 * 8))      // 16384
#define WEFF_BLOCKS (OUT_DIM * IN_DIM / (256 * 8))   // 8192

// ---------------------------------------------------------------------------
// Fused prep: blocks [0,XCVT_BLOCKS) convert x f32->bf16;
// blocks [XCVT_BLOCKS, ...) build W_eff = NF4 dequant + 2*B@A (bf16).
// Both memory-bound; fusing lets them co-schedule in one dispatch.
// ---------------------------------------------------------------------------
__global__ __launch_bounds__(256) void prep_kernel(
    const float* __restrict__ x, const int* __restrict__ codes,
    const float* __restrict__ scalers, const float* __restrict__ la,
    const float* __restrict__ lb, __bf16* __restrict__ xb,
    __bf16* __restrict__ weff) {
  if (blockIdx.x < XCVT_BLOCKS) {
    size_t g = ((size_t)blockIdx.x * 256 + threadIdx.x) * 8;
    const float4 a = *(const float4*)(x + g);
    const float4 b = *(const float4*)(x + g + 4);
    union { __bf16 h[8]; int4 i4; } u;
    u.h[0] = (__bf16)a.x; u.h[1] = (__bf16)a.y;
    u.h[2] = (__bf16)a.z; u.h[3] = (__bf16)a.w;
    u.h[4] = (__bf16)b.x; u.h[5] = (__bf16)b.y;
    u.h[6] = (__bf16)b.z; u.h[7] = (__bf16)b.w;
    *(int4*)(xb + g) = u.i4;
  } else {
    const int lane = threadIdx.x & 63;
    const float cbv = NF4_CB[lane & 15];  // lanes 0..15 hold the table
    size_t base =
        ((size_t)(blockIdx.x - XCVT_BLOCKS) * 256 + threadIdx.x) * 8;
    int o = (int)(base >> 12);          // /IN_DIM
    int k = (int)(base & (IN_DIM - 1));
    float sc = scalers[base >> 6];
    const int4 c0 = *(const int4*)(codes + base);
    const int4 c1 = *(const int4*)(codes + base + 4);
    float v[8];
    v[0] = __shfl(cbv, c0.x, 64) * sc; v[1] = __shfl(cbv, c0.y, 64) * sc;
    v[2] = __shfl(cbv, c0.z, 64) * sc; v[3] = __shfl(cbv, c0.w, 64) * sc;
    v[4] = __shfl(cbv, c1.x, 64) * sc; v[5] = __shfl(cbv, c1.y, 64) * sc;
    v[6] = __shfl(cbv, c1.z, 64) * sc; v[7] = __shfl(cbv, c1.w, 64) * sc;
    const float* lbo = lb + o * 16;
#pragma unroll
    for (int r = 0; r < 16; ++r) {
      float br = LORA_SCALE * lbo[r];
      const float4 a0 = *(const float4*)(la + r * IN_DIM + k);
      const float4 a1 = *(const float4*)(la + r * IN_DIM + k + 4);
      v[0] += br * a0.x; v[1] += br * a0.y;
      v[2] += br * a0.z; v[3] += br * a0.w;
      v[4] += br * a1.x; v[5] += br * a1.y;
      v[6] += br * a1.z; v[7] += br * a1.w;
    }
    union { __bf16 h[8]; int4 i4; } u;
#pragma unroll
    for (int t = 0; t < 8; ++t) u.h[t] = (__bf16)v[t];
    *(int4*)(weff + base) = u.i4;
  }
}

// ---------------------------------------------------------------------------
// GEMM: C[M,N] = Xb[M,K] @ Weff[N,K]^T  (bf16 in, f32 out)
// 128x128 tile, BK=32, 4 waves 2x2, 64x64/wave via 4x4 of 16x16x32 MFMA.
// DOUBLE-BUFFERED LDS, one barrier per K-step: next-tile global_load_lds
// issued before this tile's MFMAs, so the compiler's vmcnt(0)-before-barrier
// drains AFTER compute -> load latency overlapped (m99/m100 structure).
// Chunk-XOR LDS swizzle keeps bank conflicts at 0.
// ---------------------------------------------------------------------------
__global__ __launch_bounds__(256) void gemm_bt_kernel(
    const __bf16* __restrict__ A,   // [8192, 4096] x in bf16
    const __bf16* __restrict__ B,   // [4096, 4096] W_eff in bf16
    float* __restrict__ C) {        // [8192, 4096] f32
  const int K = IN_DIM;
  const int N = OUT_DIM;
  __shared__ __align__(16) __bf16 lA[2][128 * 32];
  __shared__ __align__(16) __bf16 lB[2][128 * 32];

  // supertile swizzle: 256 consecutive blocks cover 16m x 16n (n fastest)
  const int lin = blockIdx.y * gridDim.x + blockIdx.x;   // 0..2047
  const int super = lin >> 8;                            // 0..7
  const int within = lin & 255;
  const int m0 = ((super >> 1) * 16 + (within >> 4)) * 128;
  const int n0 = ((super & 1) * 16 + (within & 15)) * 128;

  const int tid = threadIdx.x;
  const int wave = tid >> 6;
  const int lane = tid & 63;
  const int wrow = wave >> 1;
  const int wcol = wave & 1;

  // staging: lane -> local row (wave*16 + lane/4), chunk XOR-swizzled
  const int srow = lane >> 2;
  const int scol = ((lane & 3) ^ ((lane >> 3) & 3)) * 8;
  const __bf16* gA = A + (size_t)(m0 + wave * 16 + srow) * K + scol;
  const __bf16* gB = B + (size_t)(n0 + wave * 16 + srow) * K + scol;
  const int ldsOff = wave * 16 * 32;   // wave-uniform base within a buffer

  f32x4 acc[4][4] = {};
  const int lm = lane & 15;
  const int lk = (((lane >> 4) ^ ((lane >> 1) & 3)) * 8);

  const __bf16* aw0 = &lA[0][(wrow * 64 + lm) * 32 + lk];
  const __bf16* bw0 = &lB[0][(wcol * 64 + lm) * 32 + lk];
  const __bf16* aw1 = &lA[1][(wrow * 64 + lm) * 32 + lk];
  const __bf16* bw1 = &lB[1][(wcol * 64 + lm) * 32 + lk];

  auto stage = [&](int koff, int buf) {
    GLOAD16(gA + koff, &lA[buf][ldsOff]);
    GLOAD16(gA + koff + (size_t)64 * K, &lA[buf][ldsOff + 64 * 32]);
    GLOAD16(gB + koff, &lB[buf][ldsOff]);
    GLOAD16(gB + koff + (size_t)64 * K, &lB[buf][ldsOff + 64 * 32]);
  };
  auto compute = [&](const __bf16* aw, const __bf16* bw) {
    bf16x8 af[4], bfp[4];
#pragma unroll
    for (int i = 0; i < 4; ++i) af[i] = *(const bf16x8*)(aw + i * 16 * 32);
#pragma unroll
    for (int j = 0; j < 4; ++j) bfp[j] = *(const bf16x8*)(bw + j * 16 * 32);
#pragma unroll
    for (int i = 0; i < 4; ++i)
#pragma unroll
      for (int j = 0; j < 4; ++j)
        acc[i][j] = __builtin_amdgcn_mfma_f32_16x16x32_bf16(af[i], bfp[j],
                                                            acc[i][j], 0, 0, 0);
  };

  stage(0, 0);
  __syncthreads();

  for (int k0 = 0; k0 < K; k0 += 64) {
    // phase 0: prefetch k0+32 -> buf1, compute buf0
    stage(k0 + 32, 1);
    compute(aw0, bw0);
    __syncthreads();
    // phase 1: prefetch k0+64 -> buf0, compute buf1
    if (k0 + 64 < K) stage(k0 + 64, 0);
    compute(aw1, bw1);
    __syncthreads();
  }

  // epilogue: D row = 4*(lane>>4)+r, col = lane&15 within each 16x16 tile
  const int crow0 = m0 + wrow * 64 + 4 * (lane >> 4);
  const int ccol0 = n0 + wcol * 64 + (lane & 15);
#pragma unroll
  for (int i = 0; i < 4; ++i)
#pragma unroll
    for (int j = 0; j < 4; ++j)
#pragma unroll
      for (int r = 0; r < 4; ++r)
        C[(size_t)(crow0 + i * 16 + r) * N + ccol0 + j * 16] = acc[i][j][r];
}

extern "C" void kernel_launch(void* const* d_in, const int* in_sizes, int n_in,
                              void* d_out, int out_size, void* d_ws,
                              size_t ws_size, hipStream_t stream) {
  const float* x = (const float*)d_in[0];       // [8192,4096]
  const int* codes = (const int*)d_in[1];       // [262144,64]
  const float* scalers = (const float*)d_in[2]; // [262144]
  const float* la = (const float*)d_in[3];      // [16,4096]
  const float* lb = (const float*)d_in[4];      // [4096,16]
  float* out = (float*)d_out;                   // [8192,4096]

  __bf16* xb = (__bf16*)d_ws;                                        // 64 MB
  __bf16* weff = (__bf16*)((char*)d_ws + (size_t)NTOK * IN_DIM * 2); // 32 MB

  prep_kernel<<<XCVT_BLOCKS + WEFF_BLOCKS, 256, 0, stream>>>(
      x, codes, scalers, la, lb, xb, weff);
  gemm_bt_kernel<<<dim3(OUT_DIM / 128, NTOK / 128), 256, 0, stream>>>(xb, weff,
                                                                      out);
}